// Round 6
// baseline (208.081 us; speedup 1.0000x reference)
//
#include <hip/hip_runtime.h>
#include <math.h>

#define NATOMS 2048
#define DIM 64

typedef float f32x4 __attribute__((ext_vector_type(4)));

// Layout: 16 lanes per pair (group g = lane>>4 = DPP row), 4 pairs/wave-iter.
// q = lane&15 owns basis dims d0 = 4q..4q+3 (consecutive -> short Chebyshev
// recurrence) and output dims 4q..4q+3 (one float4 store per lane per iter).
//
// Block = 256 threads = 4 waves; block (w, rowGroup) covers rows
// rowGroup*4+waveInBlock and the 256-column window w*256..w*256+255.
// Only the 3 KB atom window is staged in LDS; the i-atom is a one-time
// wave-uniform global read. Steady-state loop has NO global loads and NO
// DS reduce ops: the 16-lane sum is 4x v_add_f32_dpp row_ror (rotation
// reduce — a 16-lane group is exactly one DPP row), entirely VALU-pipe.
//
// t[m] = sum_d sin((d+1)*pi*x/5)/x * w1[d][m] (1/x folded into the
// Chebyshev seeds; recurrence is linear). out[o] = sqrt(2/5) * sum_m
// t[m]*w2[m][o] with sqrt(2/5) pre-folded into the w2 fragment.

template <int CTRL>
__device__ __forceinline__ float dpp_add(float v) {
    // v + dpp<CTRL>(v); GCNDPPCombine fuses to v_add_f32_dpp
    int m = __builtin_amdgcn_update_dpp(0, __float_as_int(v), CTRL, 0xF, 0xF, true);
    return v + __int_as_float(m);
}

__global__ __launch_bounds__(256, 6) void bessel_rbf_kernel(
    const float* __restrict__ atoms,
    const float* __restrict__ w1,   // (64,4)
    const float* __restrict__ w2,   // (4,64)
    float* __restrict__ out)        // (N,N,64)
{
    __shared__ float s_at[256 * 3];   // 3 KB column window

    const int tid  = threadIdx.x;
    const int lane = tid & 63;
    const int waveInBlock = tid >> 6;     // 0..3
    const int q = lane & 15;
    const int g = lane >> 4;              // 0..3 (DPP row id)
    const int d0 = q * 4;

    const int w        = (int)(blockIdx.x & 7u);   // column window
    const int rowGroup = (int)(blockIdx.x >> 3);   // 0..511
    const int i        = rowGroup * 4 + waveInBlock;
    const int colBase  = w * 256;

    // Stage the 256-atom window: 768 floats = 192 float4.
    if (tid < 192) {
        reinterpret_cast<float4*>(s_at)[tid] =
            reinterpret_cast<const float4*>(atoms)[w * 192 + tid];
    }

    // w1 rows d0..d0+3 (16 regs)
    float w1r[4][4];
#pragma unroll
    for (int k = 0; k < 4; ++k) {
        float4 v = *reinterpret_cast<const float4*>(w1 + (d0 + k) * 4);
        w1r[k][0] = v.x; w1r[k][1] = v.y; w1r[k][2] = v.z; w1r[k][3] = v.w;
    }
    // w2 columns 4q..4q+3, pre-scaled by sqrt(2/5) (16 regs)
    const float PREF = 0.6324555320336759f;
    float w2c[4][4];
#pragma unroll
    for (int m = 0; m < 4; ++m) {
        float4 v = *reinterpret_cast<const float4*>(w2 + m * DIM + 4 * q);
        w2c[m][0] = v.x * PREF; w2c[m][1] = v.y * PREF;
        w2c[m][2] = v.z * PREF; w2c[m][3] = v.w * PREF;
    }

    // i-atom: wave-uniform one-time global read (outside the loop).
    const float ax = atoms[i * 3 + 0];
    const float ay = atoms[i * 3 + 1];
    const float az = atoms[i * 3 + 2];

    __syncthreads();

    const float dk1 = (float)(d0 + 1);    // first frequency index for this lane
    f32x4* __restrict__ out4 = reinterpret_cast<f32x4*>(out);
    // Wave's first pair; all indices fit 32-bit (max f32x4 idx = 67.1M).
    const unsigned pairBase = (unsigned)i * 2048u + (unsigned)colBase;

#pragma unroll 1
    for (int it = 0; it < 64; ++it) {
        const int jl = it * 4 + g;        // local column 0..255

        const float bx = s_at[jl * 3 + 0];
        const float by = s_at[jl * 3 + 1];
        const float bz = s_at[jl * 3 + 2];

        const float dx = ax - bx, dy = ay - by, dz = az - bz;
        float x = __builtin_amdgcn_sqrtf(fmaf(dx, dx, fmaf(dy, dy, dz * dz)));
        x += 1e-8f;                               // x_ext (sin arg AND divisor)
        const float inv = __builtin_amdgcn_rcpf(x);
        const float xr  = x * 0.1f;               // step angle in revolutions

        // sin((d0+k+1)*2*pi*xr)/x, k=0..3, Chebyshev from two seeds.
        float r0 = dk1 * xr;
        float r1 = r0 + xr;
        r0 = r0 - floorf(r0);
        r1 = r1 - floorf(r1);
        float rc = xr - floorf(xr);
        const float a0   = __builtin_amdgcn_sinf(r0) * inv;
        const float a1   = __builtin_amdgcn_sinf(r1) * inv;
        const float c1   = __builtin_amdgcn_cosf(rc);
        const float twoC = c1 + c1;
        const float a2   = fmaf(twoC, a1, -a0);
        const float a3   = fmaf(twoC, a2, -a1);

        float t[4];
#pragma unroll
        for (int m = 0; m < 4; ++m) {
            t[m] = fmaf(a1, w1r[1][m], a0 * w1r[0][m]);
            t[m] = fmaf(a2, w1r[2][m], t[m]);
            t[m] = fmaf(a3, w1r[3][m], t[m]);
        }

        // Full 16-lane rotation reduce, VALU-only (row_ror: 8,4,2,1).
#pragma unroll
        for (int m = 0; m < 4; ++m) {
            t[m] = dpp_add<0x128>(t[m]);  // row_ror:8
            t[m] = dpp_add<0x124>(t[m]);  // row_ror:4
            t[m] = dpp_add<0x122>(t[m]);  // row_ror:2
            t[m] = dpp_add<0x121>(t[m]);  // row_ror:1
        }

        // Project to this lane's 4 outputs.
        f32x4 o4;
        o4.x = fmaf(t[0], w2c[0][0], fmaf(t[1], w2c[1][0], fmaf(t[2], w2c[2][0], t[3] * w2c[3][0])));
        o4.y = fmaf(t[0], w2c[0][1], fmaf(t[1], w2c[1][1], fmaf(t[2], w2c[2][1], t[3] * w2c[3][1])));
        o4.z = fmaf(t[0], w2c[0][2], fmaf(t[1], w2c[1][2], fmaf(t[2], w2c[2][2], t[3] * w2c[3][2])));
        o4.w = fmaf(t[0], w2c[0][3], fmaf(t[1], w2c[1][3], fmaf(t[2], w2c[2][3], t[3] * w2c[3][3])));

        // Pair region = 256B = 16 float4s; 16 lanes of the group cover it.
        out4[(pairBase + (unsigned)jl) * 16u + (unsigned)q] = o4;
    }
}

extern "C" void kernel_launch(void* const* d_in, const int* in_sizes, int n_in,
                              void* d_out, int out_size, void* d_ws, size_t ws_size,
                              hipStream_t stream) {
    const float* atoms = (const float*)d_in[0];
    const float* w1    = (const float*)d_in[1];
    const float* w2    = (const float*)d_in[2];
    float* out         = (float*)d_out;

    // 8 column windows x 512 row groups = 4096 blocks x 256 threads
    // = 16384 waves; each wave owns 256 contiguous pairs (64 iters x 4).
    dim3 grid(4096), block(256);
    hipLaunchKernelGGL(bessel_rbf_kernel, grid, block, 0, stream, atoms, w1, w2, out);
}

// Round 7
// 207.882 us; speedup vs baseline: 1.0010x; 1.0010x over previous
//
#include <hip/hip_runtime.h>
#include <math.h>

#define NATOMS 2048
#define DIM 64

typedef float f32x4 __attribute__((ext_vector_type(4)));

// 16 lanes per pair (group g = lane>>4 = one DPP row), 4 pairs/wave-iter.
// q = lane&15 owns basis dims 4q..4q+3 and output dims 4q..4q+3.
//
// KEY CHANGE vs R6: __launch_bounds__(256, 8) forces VGPR <= 64, crossing
// the 64-VGPR occupancy step (m69: waves/SIMD halve at 64/128) -> 8 waves
// per SIMD = 32 waves/CU, matching the fill kernel's occupancy class. The
// loop body is register-dieted to fit: i-atom coords scalarized through
// readfirstlane (SGPRs), store address is one 32-bit byte offset bumped by
// 1024/iter (saddr+voffset store form), weights 32 VGPRs, reduce all-VALU.
//
// t[m] = sum_d sin((d+1)*pi*x/5)/x * w1[d][m] (1/x folded into Chebyshev
// seeds), full 16-lane sum via 4x v_add_f32_dpp row_ror (no DS ops).
// out[o] = sqrt(2/5) * sum_m t[m]*w2[m][o], sqrt(2/5) pre-folded into w2c.

template <int CTRL>
__device__ __forceinline__ float dpp_add(float v) {
    // v + dpp<CTRL>(v); GCNDPPCombine fuses to a single v_add_f32_dpp
    int m = __builtin_amdgcn_update_dpp(0, __float_as_int(v), CTRL, 0xF, 0xF, true);
    return v + __int_as_float(m);
}

__global__ __launch_bounds__(256, 8) void bessel_rbf_kernel(
    const float* __restrict__ atoms,
    const float* __restrict__ w1,   // (64,4)
    const float* __restrict__ w2,   // (4,64)
    float* __restrict__ out)        // (N,N,64)
{
    __shared__ float s_at[256 * 3];   // 3 KB column window

    const int tid  = threadIdx.x;
    const int lane = tid & 63;
    const int q = lane & 15;
    const int g = lane >> 4;              // 0..3 (DPP row id)
    const int d0 = q * 4;

    const int w        = (int)(blockIdx.x & 7u);   // column window
    const int rowGroup = (int)(blockIdx.x >> 3);   // 0..511
    // wave-uniform row index, forced into an SGPR
    const int i = __builtin_amdgcn_readfirstlane(rowGroup * 4 + (tid >> 6));
    const int colBase  = w * 256;

    // Stage the 256-atom window: 768 floats = 192 float4.
    if (tid < 192) {
        reinterpret_cast<float4*>(s_at)[tid] =
            reinterpret_cast<const float4*>(atoms)[w * 192 + tid];
    }

    // w1 rows d0..d0+3 (16 VGPRs)
    float w1r[4][4];
#pragma unroll
    for (int k = 0; k < 4; ++k) {
        float4 v = *reinterpret_cast<const float4*>(w1 + (d0 + k) * 4);
        w1r[k][0] = v.x; w1r[k][1] = v.y; w1r[k][2] = v.z; w1r[k][3] = v.w;
    }
    // w2 columns 4q..4q+3, pre-scaled by sqrt(2/5) (16 VGPRs)
    const float PREF = 0.6324555320336759f;
    float w2c[4][4];
#pragma unroll
    for (int m = 0; m < 4; ++m) {
        float4 v = *reinterpret_cast<const float4*>(w2 + m * DIM + 4 * q);
        w2c[m][0] = v.x * PREF; w2c[m][1] = v.y * PREF;
        w2c[m][2] = v.z * PREF; w2c[m][3] = v.w * PREF;
    }

    // i-atom: uniform address (i is SGPR) -> scalar loads, coords in SGPRs.
    const float ax = atoms[i * 3 + 0];
    const float ay = atoms[i * 3 + 1];
    const float az = atoms[i * 3 + 2];

    __syncthreads();

    const float dk1 = (float)(d0 + 1);
    // 32-bit byte offset into out for this lane's first store; +1024 per iter.
    // Max value: (2047*2048 + 2047 + 3)*256 + 15*16 + 63*1024 < 2^30. Fits.
    unsigned outOff = ((unsigned)i * 2048u + (unsigned)colBase + (unsigned)g) * 256u
                    + (unsigned)q * 16u;
    char* const outBase = (char*)out;
    // LDS float index of this group's first b-atom; +12 floats per iter.
    int jf = g * 3;

#pragma unroll 1
    for (int it = 0; it < 64; ++it) {
        const float bx = s_at[jf + 0];
        const float by = s_at[jf + 1];
        const float bz = s_at[jf + 2];

        const float dx = ax - bx, dy = ay - by, dz = az - bz;
        float x = __builtin_amdgcn_sqrtf(fmaf(dx, dx, fmaf(dy, dy, dz * dz)));
        x += 1e-8f;                               // x_ext (sin arg AND divisor)
        const float inv = __builtin_amdgcn_rcpf(x);
        const float xr  = x * 0.1f;               // step angle in revolutions

        // sin((d0+k+1)*2*pi*xr)/x, k=0..3, Chebyshev from two seeds.
        float r0 = dk1 * xr;
        float r1 = r0 + xr;
        r0 = r0 - floorf(r0);
        r1 = r1 - floorf(r1);
        float rc = xr - floorf(xr);
        const float a0   = __builtin_amdgcn_sinf(r0) * inv;
        const float a1   = __builtin_amdgcn_sinf(r1) * inv;
        const float c1   = __builtin_amdgcn_cosf(rc);
        const float twoC = c1 + c1;
        const float a2   = fmaf(twoC, a1, -a0);
        const float a3   = fmaf(twoC, a2, -a1);

        float t0 = fmaf(a1, w1r[1][0], a0 * w1r[0][0]);
        float t1 = fmaf(a1, w1r[1][1], a0 * w1r[0][1]);
        float t2 = fmaf(a1, w1r[1][2], a0 * w1r[0][2]);
        float t3 = fmaf(a1, w1r[1][3], a0 * w1r[0][3]);
        t0 = fmaf(a2, w1r[2][0], t0); t0 = fmaf(a3, w1r[3][0], t0);
        t1 = fmaf(a2, w1r[2][1], t1); t1 = fmaf(a3, w1r[3][1], t1);
        t2 = fmaf(a2, w1r[2][2], t2); t2 = fmaf(a3, w1r[3][2], t2);
        t3 = fmaf(a2, w1r[2][3], t3); t3 = fmaf(a3, w1r[3][3], t3);

        // Full 16-lane rotation reduce, VALU-only (row_ror: 8,4,2,1).
        t0 = dpp_add<0x121>(dpp_add<0x122>(dpp_add<0x124>(dpp_add<0x128>(t0))));
        t1 = dpp_add<0x121>(dpp_add<0x122>(dpp_add<0x124>(dpp_add<0x128>(t1))));
        t2 = dpp_add<0x121>(dpp_add<0x122>(dpp_add<0x124>(dpp_add<0x128>(t2))));
        t3 = dpp_add<0x121>(dpp_add<0x122>(dpp_add<0x124>(dpp_add<0x128>(t3))));

        // Project to this lane's 4 outputs.
        f32x4 o4;
        o4.x = fmaf(t0, w2c[0][0], fmaf(t1, w2c[1][0], fmaf(t2, w2c[2][0], t3 * w2c[3][0])));
        o4.y = fmaf(t0, w2c[0][1], fmaf(t1, w2c[1][1], fmaf(t2, w2c[2][1], t3 * w2c[3][1])));
        o4.z = fmaf(t0, w2c[0][2], fmaf(t1, w2c[1][2], fmaf(t2, w2c[2][2], t3 * w2c[3][2])));
        o4.w = fmaf(t0, w2c[0][3], fmaf(t1, w2c[1][3], fmaf(t2, w2c[2][3], t3 * w2c[3][3])));

        *reinterpret_cast<f32x4*>(outBase + outOff) = o4;
        outOff += 1024u;   // 4 pairs * 256 B per wave-iter
        jf += 12;          // 4 atoms * 3 floats
    }
}

extern "C" void kernel_launch(void* const* d_in, const int* in_sizes, int n_in,
                              void* d_out, int out_size, void* d_ws, size_t ws_size,
                              hipStream_t stream) {
    const float* atoms = (const float*)d_in[0];
    const float* w1    = (const float*)d_in[1];
    const float* w2    = (const float*)d_in[2];
    float* out         = (float*)d_out;

    // 8 column windows x 512 row groups = 4096 blocks x 256 threads.
    // Each wave: 64 iters x 4 pairs = 256 contiguous pairs (64 KB output).
    dim3 grid(4096), block(256);
    hipLaunchKernelGGL(bessel_rbf_kernel, grid, block, 0, stream, atoms, w1, w2, out);
}

// Round 8
// 196.961 us; speedup vs baseline: 1.0565x; 1.0554x over previous
//
#include <hip/hip_runtime.h>
#include <math.h>

#define NATOMS 2048
#define DIM 64

typedef float f32x4 __attribute__((ext_vector_type(4)));

// R5 structure (best so far: 200.3 us), single change: the pair loop is
// unrolled 2-deep (was #pragma unroll 1) so the compiler interleaves two
// independent iteration chains — ILP test of the latency-bound hypothesis.
// __launch_bounds__(256,4) caps VGPR at 128 so the unroll cannot cross the
// 128-VGPR occupancy cliff (m69: waves/SIMD halve at 64/128/256).
//
// Layout: 8 lanes per pair (group g = lane>>3), 8 pairs per wave-iteration.
// q = lane&7 owns basis dims d0 = q*8..q*8+7 (consecutive -> sin Chebyshev
// recurrence) and output dims {4q..4q+3} U {32+4q..32+4q+3}.
// Each wave owns a contiguous 512-pair chunk (quarter row): i = wid>>2
// (loop-invariant), columns (wid&3)*512 + iter*8 + g. All atoms staged in
// LDS once -> steady-state loop has NO global loads (no vmcnt coupling of
// loads to the output stores).

template <int CTRL>
__device__ __forceinline__ float dpp_add(float v) {
    int m = __builtin_amdgcn_update_dpp(0, __float_as_int(v), CTRL, 0xF, 0xF, true);
    return v + __int_as_float(m);
}
__device__ __forceinline__ float swz_add_xor4(float v) {
    return v + __int_as_float(__builtin_amdgcn_ds_swizzle(__float_as_int(v), 0x101F));
}

__global__ __launch_bounds__(256, 4) void bessel_rbf_kernel(
    const float* __restrict__ atoms,
    const float* __restrict__ w1,   // (64,4)
    const float* __restrict__ w2,   // (4,64)
    float* __restrict__ out)        // (N,N,64)
{
    __shared__ float s_at[NATOMS * 3];   // 24 KB, xyz interleaved

    const int tid  = threadIdx.x;
    const int lane = tid & 63;
    const int waveInBlock = tid >> 6;
    const int q = lane & 7;
    const int g = lane >> 3;
    const int d0 = q * 8;

    // Stage all atoms to LDS: 6144 floats = 1536 float4, 256 threads x 6.
    {
        const float4* ga = reinterpret_cast<const float4*>(atoms);
        float4* sa = reinterpret_cast<float4*>(s_at);
#pragma unroll
        for (int r = 0; r < 6; ++r)
            sa[tid + 256 * r] = ga[tid + 256 * r];
    }

    // w1 rows d0..d0+7
    float w1r[8][4];
#pragma unroll
    for (int k = 0; k < 8; ++k) {
        float4 v = *reinterpret_cast<const float4*>(w1 + (d0 + k) * 4);
        w1r[k][0] = v.x; w1r[k][1] = v.y; w1r[k][2] = v.z; w1r[k][3] = v.w;
    }
    // w2 columns 4q..4q+3 (A) and 32+4q..32+4q+3 (B), pre-scaled by sqrt(2/5)
    const float PREF = 0.6324555320336759f;
    float w2a[4][4], w2b[4][4];
#pragma unroll
    for (int m = 0; m < 4; ++m) {
        float4 va = *reinterpret_cast<const float4*>(w2 + m * DIM + 4 * q);
        float4 vb = *reinterpret_cast<const float4*>(w2 + m * DIM + 32 + 4 * q);
        w2a[m][0] = va.x * PREF; w2a[m][1] = va.y * PREF;
        w2a[m][2] = va.z * PREF; w2a[m][3] = va.w * PREF;
        w2b[m][0] = vb.x * PREF; w2b[m][1] = vb.y * PREF;
        w2b[m][2] = vb.z * PREF; w2b[m][3] = vb.w * PREF;
    }

    __syncthreads();

    // Wave-contiguous chunking: wave wid owns pairs [wid*512, wid*512+512).
    const unsigned wid = __builtin_amdgcn_readfirstlane(
        (unsigned)blockIdx.x * 4u + (unsigned)waveInBlock);
    const int i       = (int)(wid >> 2);          // loop-invariant row
    const int colBase = (int)(wid & 3u) * 512;

    // i-atom (wave-uniform, from LDS broadcast)
    const float ax = s_at[i * 3 + 0];
    const float ay = s_at[i * 3 + 1];
    const float az = s_at[i * 3 + 2];

    const float dk1 = (float)(d0 + 1);
    f32x4* __restrict__ out4 = reinterpret_cast<f32x4*>(out);
    const size_t rowBase = (size_t)i * 2048 + (size_t)colBase;

#pragma unroll 2
    for (int it = 0; it < 64; ++it) {
        const int j = colBase + it * 8 + g;

        const float bx = s_at[j * 3 + 0];
        const float by = s_at[j * 3 + 1];
        const float bz = s_at[j * 3 + 2];

        const float dx = ax - bx, dy = ay - by, dz = az - bz;
        float x = __builtin_amdgcn_sqrtf(fmaf(dx, dx, fmaf(dy, dy, dz * dz)));
        x += 1e-8f;                              // x_ext (sin arg AND divisor)
        const float inv = __builtin_amdgcn_rcpf(x);
        const float xr  = x * 0.1f;              // step angle in revolutions

        // sin((d0+k+1)*2*pi*xr)/x via Chebyshev: s_{k+1} = 2c*s_k - s_{k-1}
        float r0 = dk1 * xr;
        float r1 = r0 + xr;
        r0 = r0 - floorf(r0);
        r1 = r1 - floorf(r1);
        float rc = xr - floorf(xr);
        const float a0   = __builtin_amdgcn_sinf(r0) * inv;
        const float a1   = __builtin_amdgcn_sinf(r1) * inv;
        const float c1   = __builtin_amdgcn_cosf(rc);
        const float twoC = c1 + c1;

        float t[4];
#pragma unroll
        for (int m = 0; m < 4; ++m)
            t[m] = fmaf(a1, w1r[1][m], a0 * w1r[0][m]);
        float sp = a0, sc = a1;
#pragma unroll
        for (int k = 2; k < 8; ++k) {
            const float sn = fmaf(twoC, sc, -sp);
#pragma unroll
            for (int m = 0; m < 4; ++m)
                t[m] = fmaf(sn, w1r[k][m], t[m]);
            sp = sc; sc = sn;
        }

        // Reduce across the 8 lanes of this group.
#pragma unroll
        for (int m = 0; m < 4; ++m) {
            t[m] = dpp_add<0xB1>(t[m]);   // xor1: quad_perm [1,0,3,2]
            t[m] = dpp_add<0x4E>(t[m]);   // xor2: quad_perm [2,3,0,1]
            t[m] = swz_add_xor4(t[m]);    // xor4: ds_swizzle
        }

        // Project to this lane's 8 outputs.
        f32x4 oA, oB;
        oA.x = fmaf(t[0], w2a[0][0], fmaf(t[1], w2a[1][0], fmaf(t[2], w2a[2][0], t[3] * w2a[3][0])));
        oA.y = fmaf(t[0], w2a[0][1], fmaf(t[1], w2a[1][1], fmaf(t[2], w2a[2][1], t[3] * w2a[3][1])));
        oA.z = fmaf(t[0], w2a[0][2], fmaf(t[1], w2a[1][2], fmaf(t[2], w2a[2][2], t[3] * w2a[3][2])));
        oA.w = fmaf(t[0], w2a[0][3], fmaf(t[1], w2a[1][3], fmaf(t[2], w2a[2][3], t[3] * w2a[3][3])));
        oB.x = fmaf(t[0], w2b[0][0], fmaf(t[1], w2b[1][0], fmaf(t[2], w2b[2][0], t[3] * w2b[3][0])));
        oB.y = fmaf(t[0], w2b[0][1], fmaf(t[1], w2b[1][1], fmaf(t[2], w2b[2][1], t[3] * w2b[3][1])));
        oB.z = fmaf(t[0], w2b[0][2], fmaf(t[1], w2b[1][2], fmaf(t[2], w2b[2][2], t[3] * w2b[3][2])));
        oB.w = fmaf(t[0], w2b[0][3], fmaf(t[1], w2b[1][3], fmaf(t[2], w2b[2][3], t[3] * w2b[3][3])));

        const size_t base = (rowBase + (size_t)(it * 8 + g)) * 16;
        out4[base + q]     = oA;
        out4[base + 8 + q] = oB;
    }
}

extern "C" void kernel_launch(void* const* d_in, const int* in_sizes, int n_in,
                              void* d_out, int out_size, void* d_ws, size_t ws_size,
                              hipStream_t stream) {
    const float* atoms = (const float*)d_in[0];
    const float* w1    = (const float*)d_in[1];
    const float* w2    = (const float*)d_in[2];
    float* out         = (float*)d_out;

    // 2048 blocks x 256 threads = 8192 waves; each wave owns 512 contiguous
    // pairs (64 iterations x 8 pairs).
    dim3 grid(2048), block(256);
    hipLaunchKernelGGL(bessel_rbf_kernel, grid, block, 0, stream, atoms, w1, w2, out);
}